// Round 12
// baseline (513.580 us; speedup 1.0000x reference)
//
#include <hip/hip_runtime.h>
#include <hip/hip_bf16.h>
#include <math.h>

// Fused GNN readout via bf16 MFMA (v_mfma_f32_32x32x16_bf16):
//   feat1 = relu(concat(h,x) @ W1 + b1)   [N,256]  GEMM1: K=400(pad 448), A=bf16 hi, B=W1 hi ONLY
//   feat2 = relu(feat1 @ W2 + b2)         [N,64]   GEMM2: K=256, A=bf16 hi, B=W2 hi+lo
//   s_n   = feat2 . Wout ; out = sigmoid(segment_sum(s_n) + bout)
// R12 = R11 + replay-race fix:
//   R11's vmcnt(8) was EXACT (0 slack): LLVM could hoist SSTEP B-loads above
//   the AISSUE global_load_lds batch, breaking the count => stale-LDS race
//   visible only on warm graph replays. Fix (rule #18/#21):
//   - sched_barrier(0) right after every AISSUE pins A-issue order;
//   - waits get margin: vmcnt(2) at chunk 0, vmcnt(4) after (exact need is 8).

typedef __attribute__((ext_vector_type(8)))  short short8v;
typedef __attribute__((ext_vector_type(16))) float f32x16;

#define G_NUM 2048
#define HID 200
#define EMB 200
#define DIN 400
#define NH1 256
#define NH2 64
#define BM  64
#define NKS1 28        // bf16 K-steps (of 16) for GEMM1, K padded 400->448
#define NCH  7         // 7 chunks of 64 fp32 cols
#define NKS2 16        // K-steps for GEMM2 (K=256)

#define W1P_SH8 (NKS1*8*64)   // 14336 fragments (16B each), hi plane only
#define W2P_SH8 (NKS2*2*64)   // 2048

__device__ __forceinline__ unsigned short f2bf(float f) {
    union { float f; unsigned u; } v; v.f = f;
    unsigned r = v.u + 0x7fffu + ((v.u >> 16) & 1u);   // RNE
    return (unsigned short)(r >> 16);
}
__device__ __forceinline__ float bf2f(unsigned short b) {
    union { unsigned u; float f; } v; v.u = ((unsigned)b) << 16;
    return v.f;
}
// 8 fp32 -> 8 bf16 (RNE) via packed converts
__device__ __forceinline__ short8v cvt8(float4 a, float4 b) {
    union { __hip_bfloat162 q[4]; short8v s8; } u;
    u.q[0] = __float22bfloat162_rn(make_float2(a.x, a.y));
    u.q[1] = __float22bfloat162_rn(make_float2(a.z, a.w));
    u.q[2] = __float22bfloat162_rn(make_float2(b.x, b.y));
    u.q[3] = __float22bfloat162_rn(make_float2(b.z, b.w));
    return u.s8;
}

// Pre-pack W1 (hi only) / W2 (hi+lo) into MFMA-fragment order.
// Fragment (ks, ntile, lane) holds 8 bf16: B[k0+j][col], k0=ks*16+(lane>>5)*8,
// col=ntile*32+(lane&31). Contiguous-8 k in BOTH A and B => any consistent
// hw k-permutation cancels in the dot product.
__global__ void pack_weights(const float* __restrict__ W1, const float* __restrict__ W2,
                             unsigned short* __restrict__ w1h,
                             unsigned short* __restrict__ w2h, unsigned short* __restrict__ w2l)
{
    int idx = blockIdx.x * 256 + threadIdx.x;
    if (idx < W1P_SH8) {
        int l  = idx & 63;
        int nt = (idx >> 6) & 7;
        int ks = idx >> 9;
        int col = nt * 32 + (l & 31);
        int k0  = ks * 16 + (l >> 5) * 8;
        short8v H;
        #pragma unroll
        for (int j = 0; j < 8; ++j) {
            int k = k0 + j;
            H[j] = (short)f2bf((k < DIN) ? W1[(size_t)k * NH1 + col] : 0.f);
        }
        ((short8v*)w1h)[idx] = H;
    } else if (idx < W1P_SH8 + W2P_SH8) {
        int i2 = idx - W1P_SH8;
        int l  = i2 & 63;
        int nt = (i2 >> 6) & 1;
        int ks = i2 >> 7;
        int col = nt * 32 + (l & 31);
        int k0  = ks * 16 + (l >> 5) * 8;
        short8v H, L;
        #pragma unroll
        for (int j = 0; j < 8; ++j) {
            float v = W2[(size_t)(k0 + j) * NH2 + col];
            unsigned short hh = f2bf(v);
            H[j] = (short)hh;
            L[j] = (short)f2bf(v - bf2f(hh));
        }
        ((short8v*)w2h)[i2] = H;
        ((short8v*)w2l)[i2] = L;
    }
}

__launch_bounds__(256, 4)
__global__ void fused_readout(const float* __restrict__ h, const float* __restrict__ x,
                              const int* __restrict__ batch,
                              const unsigned short* __restrict__ w1h,
                              const unsigned short* __restrict__ w2h, const unsigned short* __restrict__ w2l,
                              const float* __restrict__ b1, const float* __restrict__ b2,
                              const float* __restrict__ Wout, const float* __restrict__ zbuf,
                              float* __restrict__ gf1d, int N)
{
    // LDS: 2 DISJOINT ring buffers, 16 KiB each ([64 rows][64 fp32], row stride
    // 256B, 16B-granule XOR swizzle c16 ^= row&15 applied on the GLOBAL SOURCE;
    // LDS dest linear for global_load_lds) + small pool buffer. Total 33536 B
    // -> 4 blocks/CU. Chunk c reads ring c&1; A(c+1) issued at top of chunk c.
    // After the k-loop: F1h rows 0-31 -> R0, rows 32-63 -> R1 (bf16, swizzled).
    __shared__ __align__(16) float R0[4096];
    __shared__ __align__(16) float R1[4096];
    __shared__ __align__(16) float R2s[192];

    const int t    = threadIdx.x;
    const int lane = t & 63;
    const int w    = t >> 6;
    const int n0   = blockIdx.x * BM;
    const int l31  = lane & 31;
    const int hs   = lane >> 5;         // k-half select

    const short8v* W1H = (const short8v*)w1h;

    f32x16 acc00, acc01, acc10, acc11;
    #pragma unroll
    for (int r = 0; r < 16; ++r) { acc00[r] = 0.f; acc01[r] = 0.f; acc10[r] = 0.f; acc11[r] = 0.f; }

    // ---- helpers ----
    #define AISSUE(CH, RP) do {                                                \
        _Pragma("unroll")                                                      \
        for (int ii = 0; ii < 4; ++ii) {                                       \
            int brow = w*16 + ii*4;                                            \
            int row  = brow + (lane >> 4);                                     \
            int node = n0 + row;                                               \
            int colf = (CH)*64 + (((lane & 15) ^ (row & 15)) << 2);            \
            const float* src;                                                  \
            if (node >= N || colf >= DIN) src = zbuf + (lane & 15)*4;          \
            else if (colf < HID)          src = h + (size_t)node*HID + colf;   \
            else                          src = x + (size_t)node*EMB + (colf - HID); \
            __builtin_amdgcn_global_load_lds(                                  \
                (const __attribute__((address_space(1))) unsigned*)src,        \
                (__attribute__((address_space(3))) unsigned*)((char*)(RP) + brow*256 + lane*16), \
                16, 0, 0);                                                     \
        }                                                                      \
        __builtin_amdgcn_sched_barrier(0);  /* pin: A-issue precedes B loads */ \
    } while (0)

    // A fragment: row ROW, logical col16 pair {S*4+hs*2, +1} of ring RP
    #define AFRAG(RP, S, ROW)                                                  \
        cvt8(*(const float4*)((const char*)(RP) + (ROW)*256 + ((((S)*4 + hs*2)     ^ ((ROW) & 15)) << 4)), \
             *(const float4*)((const char*)(RP) + (ROW)*256 + ((((S)*4 + hs*2 + 1) ^ ((ROW) & 15)) << 4)))

    #define BLOAD2(KS, H0, H1) do {                                            \
        size_t nb_ = ((size_t)((KS)*8 + w*2))*64 + lane;                       \
        H0 = W1H[nb_]; H1 = W1H[nb_ + 64]; } while (0)

    // one k-step: prefetch B(ks+2) hi, read+convert A hi frags, 4 MFMAs
    #define SSTEP(KSN, RP, S) do {                                             \
        short8v nb0, nb1;                                                      \
        BLOAD2((KSN), nb0, nb1);                                               \
        short8v ah0 = AFRAG(RP, S, l31);                                       \
        short8v ah1 = AFRAG(RP, S, 32 + l31);                                  \
        __builtin_amdgcn_s_setprio(1);                                         \
        acc00 = __builtin_amdgcn_mfma_f32_32x32x16_bf16(ah0, b0h0, acc00, 0,0,0); \
        acc01 = __builtin_amdgcn_mfma_f32_32x32x16_bf16(ah0, b0h1, acc01, 0,0,0); \
        acc10 = __builtin_amdgcn_mfma_f32_32x32x16_bf16(ah1, b0h0, acc10, 0,0,0); \
        acc11 = __builtin_amdgcn_mfma_f32_32x32x16_bf16(ah1, b0h1, acc11, 0,0,0); \
        __builtin_amdgcn_s_setprio(0);                                         \
        b0h0 = b1h0; b0h1 = b1h1; b1h0 = nb0; b1h1 = nb1;                      \
    } while (0)

    #define KC(K) ((K) < NKS1 ? (K) : 0)

    // one chunk: counted wait (with margin, never 0), barrier, issue A(C+1)
    #define CHUNK(C, RCUR, VMC, DOISS, RNXT) do {                              \
        asm volatile("s_waitcnt vmcnt(" #VMC ")" ::: "memory");                \
        __builtin_amdgcn_s_barrier();                                          \
        if (DOISS) { AISSUE((C)+1, RNXT); }                                    \
        SSTEP(KC((C)*4+2), RCUR, 0);                                           \
        SSTEP(KC((C)*4+3), RCUR, 1);                                           \
        SSTEP(KC((C)*4+4), RCUR, 2);                                           \
        SSTEP(KC((C)*4+5), RCUR, 3);                                           \
    } while (0)

    // ---- prologue: A chunk 0 in flight; B pipe depth 2 ----
    AISSUE(0, R0);
    short8v b0h0, b0h1, b1h0, b1h1;
    BLOAD2(0, b0h0, b0h1);
    BLOAD2(1, b1h0, b1h1);

    // ================= GEMM1: 7 chunks x 4 k-steps, 2-ring counted-vmcnt =================
    // Ops newer than A(c) at top of chunk c: exactly 8 B loads (4 at c=0),
    // order pinned by sched_barrier. Waits use margin 4 (2 at c=0): the extra
    // forced completions are B loads already consumed by SSTEP0/1.
    CHUNK(0, R0, 2, true,  R1);
    CHUNK(1, R1, 4, true,  R0);
    CHUNK(2, R0, 4, true,  R1);
    CHUNK(3, R1, 4, true,  R0);
    CHUNK(4, R0, 4, true,  R1);
    CHUNK(5, R1, 4, true,  R0);
    CHUNK(6, R0, 4, false, R1);

    #undef CHUNK
    #undef KC
    #undef SSTEP
    #undef BLOAD2
    #undef AFRAG
    #undef AISSUE

    __syncthreads();   // full drain (one-time); rings reusable as F1h

    // ---- epilogue1: bias + relu + bf16 (hi only) -> F1h (XOR-swizzled) ----
    // F1h rows 0-31 -> R0, rows 32-63 -> R1.
    // C/D layout: col = lane&31, row = (r&3) + 8*(r>>2) + 4*(lane>>5)
    unsigned short* F1hA = (unsigned short*)R0;
    unsigned short* F1hB = (unsigned short*)R1;
    const float b1c0 = b1[w*64 + l31];
    const float b1c1 = b1[w*64 + 32 + l31];
#define EPI1(ACC, FH, NI) do {                                            \
        int gcol = w*64 + (NI)*32 + l31;                                  \
        float bb = (NI) ? b1c1 : b1c0;                                    \
        _Pragma("unroll")                                                 \
        for (int r = 0; r < 16; ++r) {                                    \
            int lrow = (r & 3) + 8*(r >> 2) + 4*hs;   /* 0..31 */         \
            float v = fmaxf(ACC[r] + bb, 0.f);                            \
            int phys = lrow*256 + (((gcol >> 3) ^ lrow) << 3) + (gcol & 7); \
            FH[phys] = f2bf(v);                                           \
        } } while (0)
    EPI1(acc00, F1hA, 0); EPI1(acc01, F1hA, 1); EPI1(acc10, F1hB, 0); EPI1(acc11, F1hB, 1);
#undef EPI1
    __syncthreads();

    // ================= GEMM2: feat2 = relu(feat1 @ W2 + b2) =================
    // A = bf16(feat1) hi-only; B = W2 hi+lo (2 MFMAs per K-step).
    f32x16 acc2;
    #pragma unroll
    for (int r = 0; r < 16; ++r) acc2[r] = 0.f;
    const int m2   = w >> 1;      // node-row half
    const int nt2  = w & 1;       // col half
    const unsigned short* F1rd = m2 ? F1hB : F1hA;   // local rows 0..31 = l31

    const short8v* W2H = (const short8v*)w2h;
    const short8v* W2L = (const short8v*)w2l;
    short8v bhc = W2H[(size_t)nt2*64 + lane];
    short8v blc = W2L[(size_t)nt2*64 + lane];
    #pragma unroll
    for (int ks = 0; ks < NKS2; ++ks) {
        short8v bhn = bhc, bln = blc;
        if (ks + 1 < NKS2) {
            size_t nbase = (size_t)((ks + 1)*2 + nt2)*64 + lane;
            bhn = W2H[nbase];
            bln = W2L[nbase];
        }
        int blk  = (ks*2 + hs) ^ l31;
        short8v ah2 = *(const short8v*)&F1rd[l31*256 + blk*8];
        acc2 = __builtin_amdgcn_mfma_f32_32x32x16_bf16(ah2, bhc, acc2, 0,0,0);
        acc2 = __builtin_amdgcn_mfma_f32_32x32x16_bf16(ah2, blc, acc2, 0,0,0);
        bhc = bhn; blc = bln;
    }
    __syncthreads();   // all F1 reads done

    // ---- epilogue2: s_n = relu(feat2 + b2) . Wout, 32-col shfl reduce ----
    float* s2p  = R2s;          // 128 floats
    float* srow = R2s + 128;    // 64 floats
    {
        const int   col2 = nt2*32 + l31;
        const float b2c  = b2[col2];
        const float woc  = Wout[col2];
        #pragma unroll
        for (int r = 0; r < 16; ++r) {
            float v = fmaxf(acc2[r] + b2c, 0.f) * woc;
            v += __shfl_xor(v, 1);
            v += __shfl_xor(v, 2);
            v += __shfl_xor(v, 4);
            v += __shfl_xor(v, 8);
            v += __shfl_xor(v, 16);
            if (l31 == 0) {
                int grow = m2*32 + (r & 3) + 8*(r >> 2) + 4*hs;
                s2p[nt2*64 + grow] = v;   // [colhalf][row]
            }
        }
    }
    __syncthreads();
    if (t < 64) srow[t] = s2p[t] + s2p[64 + t];
    __syncthreads();

    // ---- segmented sum over sorted batch, one atomic per run ----
    if (t < 64) {
        int node = n0 + t;
        int b = (node < N) ? batch[node] : -1;
        int pb = (t == 0) ? -2 : ((node - 1 < N) ? batch[node - 1] : -1);
        if (b >= 0 && b != pb) {
            float acc = 0.f;
            int j = t;
            while (j < 64 && (n0 + j) < N && batch[n0 + j] == b) { acc += srow[j]; ++j; }
            atomicAdd(&gf1d[b], acc);
        }
    }
}

__global__ void final_sigmoid(const float* __restrict__ gf1d, const float* __restrict__ bout,
                              float* __restrict__ out, int G)
{
    int g = blockIdx.x * 256 + threadIdx.x;
    if (g < G) out[g] = 1.f / (1.f + expf(-(gf1d[g] + bout[0])));
}

extern "C" void kernel_launch(void* const* d_in, const int* in_sizes, int n_in,
                              void* d_out, int out_size, void* d_ws, size_t ws_size,
                              hipStream_t stream)
{
    const float* h    = (const float*)d_in[0];
    const float* x    = (const float*)d_in[1];
    const int*   batch= (const int*)d_in[2];
    const float* W1   = (const float*)d_in[3];
    const float* b1   = (const float*)d_in[4];
    const float* W2   = (const float*)d_in[5];
    const float* b2   = (const float*)d_in[6];
    const float* Wout = (const float*)d_in[7];
    const float* bout = (const float*)d_in[8];
    float* out = (float*)d_out;

    const int N = in_sizes[2];
    const int G = out_size;

    // workspace layout (~305 KB total)
    char* ws = (char*)d_ws;
    float* gf1d = (float*)ws;                                  //   8,192 B
    float* zbuf = (float*)(ws + 8192);                         //   1,024 B (zeros)
    unsigned short* w1h = (unsigned short*)(ws + 9216);        // 229,376 B
    unsigned short* w2h = w1h + (size_t)W1P_SH8 * 8;           //  32,768 B
    unsigned short* w2l = w2h + (size_t)W2P_SH8 * 8;           //  32,768 B

    hipMemsetAsync(gf1d, 0, 9216, stream);   // gf accumulators + zero buffer
    pack_weights<<<(W1P_SH8 + W2P_SH8 + 255) / 256, 256, 0, stream>>>(W1, W2, w1h, w2h, w2l);
    fused_readout<<<(N + BM - 1) / BM, 256, 0, stream>>>(h, x, batch, w1h, w2h, w2l,
                                                         b1, b2, Wout, zbuf, gf1d, N);
    final_sigmoid<<<(G + 255) / 256, 256, 0, stream>>>(gf1d, bout, out, G);
}

// Round 13
// 393.049 us; speedup vs baseline: 1.3067x; 1.3067x over previous
//
#include <hip/hip_runtime.h>
#include <hip/hip_bf16.h>
#include <math.h>

// Fused GNN readout via bf16 MFMA (v_mfma_f32_32x32x16_bf16):
//   feat1 = relu(concat(h,x) @ W1 + b1)   [N,256]  GEMM1: K=400(pad 448), A=bf16 hi, B=W1 hi ONLY
//   feat2 = relu(feat1 @ W2 + b2)         [N,64]   GEMM2: K=256, A=bf16 hi, B=W2 hi+lo
//   s_n   = feat2 . Wout ; out = sigmoid(segment_sum(s_n) + bout)
// R13 = R8 (proven 207us, WRITE 9MB, 3 blocks/CU) + two validated deltas:
//   - W1 hi-only (R10/R12 proved absmax identical 1.907e-6): 4 MFMA/SSTEP,
//     half the B traffic, B-pipe regs 32->16 (MORE headroom, not less).
//   - sched_barrier(0) after AISSUE + margin'd counted vmcnt (R12-proven
//     replay-race fix; never exact, never 0).
// Register discipline (R4/R10/R11/R12 lesson): this structure needs ~80 arch
// VGPRs -> 3 blocks/CU budget (170). Do NOT chase 4 blocks/CU.

typedef __attribute__((ext_vector_type(8)))  short short8v;
typedef __attribute__((ext_vector_type(16))) float f32x16;

#define G_NUM 2048
#define HID 200
#define EMB 200
#define DIN 400
#define NH1 256
#define NH2 64
#define BM  64
#define NKS1 28        // bf16 K-steps (of 16) for GEMM1, K padded 400->448
#define NCH  7         // 7 chunks of 64 fp32 cols
#define NKS2 16        // K-steps for GEMM2 (K=256)

#define W1P_SH8 (NKS1*8*64)   // 14336 fragments (16B each), hi plane only
#define W2P_SH8 (NKS2*2*64)   // 2048

__device__ __forceinline__ unsigned short f2bf(float f) {
    union { float f; unsigned u; } v; v.f = f;
    unsigned r = v.u + 0x7fffu + ((v.u >> 16) & 1u);   // RNE
    return (unsigned short)(r >> 16);
}
__device__ __forceinline__ float bf2f(unsigned short b) {
    union { unsigned u; float f; } v; v.u = ((unsigned)b) << 16;
    return v.f;
}
// 8 fp32 -> 8 bf16 (RNE) via packed converts
__device__ __forceinline__ short8v cvt8(float4 a, float4 b) {
    union { __hip_bfloat162 q[4]; short8v s8; } u;
    u.q[0] = __float22bfloat162_rn(make_float2(a.x, a.y));
    u.q[1] = __float22bfloat162_rn(make_float2(a.z, a.w));
    u.q[2] = __float22bfloat162_rn(make_float2(b.x, b.y));
    u.q[3] = __float22bfloat162_rn(make_float2(b.z, b.w));
    return u.s8;
}

// Pre-pack W1 (hi only) / W2 (hi+lo) into MFMA-fragment order.
// Fragment (ks, ntile, lane) holds 8 bf16: B[k0+j][col], k0=ks*16+(lane>>5)*8,
// col=ntile*32+(lane&31). Contiguous-8 k in BOTH A and B => any consistent
// hw k-permutation cancels in the dot product.
__global__ void pack_weights(const float* __restrict__ W1, const float* __restrict__ W2,
                             unsigned short* __restrict__ w1h,
                             unsigned short* __restrict__ w2h, unsigned short* __restrict__ w2l)
{
    int idx = blockIdx.x * 256 + threadIdx.x;
    if (idx < W1P_SH8) {
        int l  = idx & 63;
        int nt = (idx >> 6) & 7;
        int ks = idx >> 9;
        int col = nt * 32 + (l & 31);
        int k0  = ks * 16 + (l >> 5) * 8;
        short8v H;
        #pragma unroll
        for (int j = 0; j < 8; ++j) {
            int k = k0 + j;
            H[j] = (short)f2bf((k < DIN) ? W1[(size_t)k * NH1 + col] : 0.f);
        }
        ((short8v*)w1h)[idx] = H;
    } else if (idx < W1P_SH8 + W2P_SH8) {
        int i2 = idx - W1P_SH8;
        int l  = i2 & 63;
        int nt = (i2 >> 6) & 1;
        int ks = i2 >> 7;
        int col = nt * 32 + (l & 31);
        int k0  = ks * 16 + (l >> 5) * 8;
        short8v H, L;
        #pragma unroll
        for (int j = 0; j < 8; ++j) {
            float v = W2[(size_t)(k0 + j) * NH2 + col];
            unsigned short hh = f2bf(v);
            H[j] = (short)hh;
            L[j] = (short)f2bf(v - bf2f(hh));
        }
        ((short8v*)w2h)[i2] = H;
        ((short8v*)w2l)[i2] = L;
    }
}

__launch_bounds__(256, 3)
__global__ void fused_readout(const float* __restrict__ h, const float* __restrict__ x,
                              const int* __restrict__ batch,
                              const unsigned short* __restrict__ w1h,
                              const unsigned short* __restrict__ w2h, const unsigned short* __restrict__ w2l,
                              const float* __restrict__ b1, const float* __restrict__ b2,
                              const float* __restrict__ Wout, const float* __restrict__ zbuf,
                              float* __restrict__ gf1d, int N)
{
    // 49152 B LDS: 3 DISJOINT ring buffers, 16 KiB each ([64 rows][64 fp32],
    // row stride 256B, 16B-granule XOR swizzle c16 ^= row&15 applied on the
    // GLOBAL SOURCE; LDS dest linear for global_load_lds). Chunk c -> ring c%3,
    // issued 2 chunks ahead. After the k-loop (full __syncthreads):
    // F1h rows 0-31 -> R0, rows 32-63 -> R1 (bf16, swizzled); s2p/srow -> R2.
    __shared__ __align__(16) float R0[4096];
    __shared__ __align__(16) float R1[4096];
    __shared__ __align__(16) float R2[4096];

    const int t    = threadIdx.x;
    const int lane = t & 63;
    const int w    = t >> 6;
    const int n0   = blockIdx.x * BM;
    const int l31  = lane & 31;
    const int hs   = lane >> 5;         // k-half select

    const short8v* W1H = (const short8v*)w1h;

    f32x16 acc00, acc01, acc10, acc11;
    #pragma unroll
    for (int r = 0; r < 16; ++r) { acc00[r] = 0.f; acc01[r] = 0.f; acc10[r] = 0.f; acc11[r] = 0.f; }

    // ---- helpers ----
    #define AISSUE(CH, RP) do {                                                \
        _Pragma("unroll")                                                      \
        for (int ii = 0; ii < 4; ++ii) {                                       \
            int brow = w*16 + ii*4;                                            \
            int row  = brow + (lane >> 4);                                     \
            int node = n0 + row;                                               \
            int colf = (CH)*64 + (((lane & 15) ^ (row & 15)) << 2);            \
            const float* src;                                                  \
            if (node >= N || colf >= DIN) src = zbuf + (lane & 15)*4;          \
            else if (colf < HID)          src = h + (size_t)node*HID + colf;   \
            else                          src = x + (size_t)node*EMB + (colf - HID); \
            __builtin_amdgcn_global_load_lds(                                  \
                (const __attribute__((address_space(1))) unsigned*)src,        \
                (__attribute__((address_space(3))) unsigned*)((char*)(RP) + brow*256 + lane*16), \
                16, 0, 0);                                                     \
        }                                                                      \
        __builtin_amdgcn_sched_barrier(0);  /* pin: A-issue precedes B loads */ \
    } while (0)

    // A fragment: row ROW, logical col16 pair {S*4+hs*2, +1} of ring RP
    #define AFRAG(RP, S, ROW)                                                  \
        cvt8(*(const float4*)((const char*)(RP) + (ROW)*256 + ((((S)*4 + hs*2)     ^ ((ROW) & 15)) << 4)), \
             *(const float4*)((const char*)(RP) + (ROW)*256 + ((((S)*4 + hs*2 + 1) ^ ((ROW) & 15)) << 4)))

    #define BLOAD2(KS, H0, H1) do {                                            \
        size_t nb_ = ((size_t)((KS)*8 + w*2))*64 + lane;                       \
        H0 = W1H[nb_]; H1 = W1H[nb_ + 64]; } while (0)

    #define KC(K) ((K) < NKS1 ? (K) : 0)

    // one k-step: prefetch B(ks+2) hi, read+convert A hi frags, 4 MFMAs
    #define SSTEP(KSN, RP, S) do {                                             \
        short8v nb0, nb1;                                                      \
        BLOAD2((KSN), nb0, nb1);                                               \
        short8v ah0 = AFRAG(RP, S, l31);                                       \
        short8v ah1 = AFRAG(RP, S, 32 + l31);                                  \
        __builtin_amdgcn_s_setprio(1);                                         \
        acc00 = __builtin_amdgcn_mfma_f32_32x32x16_bf16(ah0, b0h0, acc00, 0,0,0); \
        acc01 = __builtin_amdgcn_mfma_f32_32x32x16_bf16(ah0, b0h1, acc01, 0,0,0); \
        acc10 = __builtin_amdgcn_mfma_f32_32x32x16_bf16(ah1, b0h0, acc10, 0,0,0); \
        acc11 = __builtin_amdgcn_mfma_f32_32x32x16_bf16(ah1, b0h1, acc11, 0,0,0); \
        __builtin_amdgcn_s_setprio(0);                                         \
        b0h0 = b1h0; b0h1 = b1h1; b1h0 = nb0; b1h1 = nb1;                      \
    } while (0)

    // one chunk: counted wait (margin'd, never 0), barrier, issue A(C+2)
    #define CHUNK(C, RCUR, VMC, DOISS, RISS) do {                              \
        asm volatile("s_waitcnt vmcnt(" #VMC ")" ::: "memory");                \
        __builtin_amdgcn_s_barrier();                                          \
        if (DOISS) { AISSUE((C)+2, RISS); }                                    \
        SSTEP(KC((C)*4+2), RCUR, 0);                                           \
        SSTEP(KC((C)*4+3), RCUR, 1);                                           \
        SSTEP(KC((C)*4+4), RCUR, 2);                                           \
        SSTEP(KC((C)*4+5), RCUR, 3);                                           \
    } while (0)

    // ---- prologue: A chunks 0,1 in flight; B pipe depth 2 ----
    AISSUE(0, R0);
    AISSUE(1, R1);
    short8v b0h0, b0h1, b1h0, b1h1;
    BLOAD2(0, b0h0, b0h1);
    BLOAD2(1, b1h0, b1h1);

    // ================= GEMM1: 7 chunks x 4 k-steps, 3-ring counted-vmcnt =================
    // Issue order (pinned): A0,A1,Bpro(4) | c0: A2,B(8) | c1: A3,B(8) | ... | c4: A6,B(8) | c5,c6: B(8).
    // Ops newer than A(c) at its wait: c0:8, c1:16, c2-5:20, c6:16.
    // Waits use margin >=4 (forced-early completions are B loads consumed
    // within the next 1-2 SSTEPs anyway).
    CHUNK(0, R0,  4, true,  R2);
    CHUNK(1, R1,  8, true,  R0);
    CHUNK(2, R2, 12, true,  R1);
    CHUNK(3, R0, 12, true,  R2);
    CHUNK(4, R1, 12, true,  R0);
    CHUNK(5, R2, 12, false, R0);
    CHUNK(6, R0,  8, false, R0);

    #undef CHUNK
    #undef SSTEP
    #undef KC
    #undef BLOAD2
    #undef AFRAG
    #undef AISSUE

    __syncthreads();   // full drain (one-time); rings reusable as F1h

    // ---- epilogue1: bias + relu + bf16 (hi only) -> F1h (XOR-swizzled) ----
    // F1h rows 0-31 -> R0, rows 32-63 -> R1.
    // C/D layout: col = lane&31, row = (r&3) + 8*(r>>2) + 4*(lane>>5)
    unsigned short* F1hA = (unsigned short*)R0;
    unsigned short* F1hB = (unsigned short*)R1;
    const float b1c0 = b1[w*64 + l31];
    const float b1c1 = b1[w*64 + 32 + l31];
#define EPI1(ACC, FH, NI) do {                                            \
        int gcol = w*64 + (NI)*32 + l31;                                  \
        float bb = (NI) ? b1c1 : b1c0;                                    \
        _Pragma("unroll")                                                 \
        for (int r = 0; r < 16; ++r) {                                    \
            int lrow = (r & 3) + 8*(r >> 2) + 4*hs;   /* 0..31 */         \
            float v = fmaxf(ACC[r] + bb, 0.f);                            \
            int phys = lrow*256 + (((gcol >> 3) ^ lrow) << 3) + (gcol & 7); \
            FH[phys] = f2bf(v);                                           \
        } } while (0)
    EPI1(acc00, F1hA, 0); EPI1(acc01, F1hA, 1); EPI1(acc10, F1hB, 0); EPI1(acc11, F1hB, 1);
#undef EPI1
    __syncthreads();

    // ================= GEMM2: feat2 = relu(feat1 @ W2 + b2) =================
    // A = bf16(feat1) hi-only; B = W2 hi+lo (2 MFMAs per K-step).
    f32x16 acc2;
    #pragma unroll
    for (int r = 0; r < 16; ++r) acc2[r] = 0.f;
    const int m2   = w >> 1;      // node-row half
    const int nt2  = w & 1;       // col half
    const unsigned short* F1rd = m2 ? F1hB : F1hA;   // local rows 0..31 = l31

    const short8v* W2H = (const short8v*)w2h;
    const short8v* W2L = (const short8v*)w2l;
    short8v bhc = W2H[(size_t)nt2*64 + lane];
    short8v blc = W2L[(size_t)nt2*64 + lane];
    #pragma unroll
    for (int ks = 0; ks < NKS2; ++ks) {
        short8v bhn = bhc, bln = blc;
        if (ks + 1 < NKS2) {
            size_t nbase = (size_t)((ks + 1)*2 + nt2)*64 + lane;
            bhn = W2H[nbase];
            bln = W2L[nbase];
        }
        int blk  = (ks*2 + hs) ^ l31;
        short8v ah2 = *(const short8v*)&F1rd[l31*256 + blk*8];
        acc2 = __builtin_amdgcn_mfma_f32_32x32x16_bf16(ah2, bhc, acc2, 0,0,0);
        acc2 = __builtin_amdgcn_mfma_f32_32x32x16_bf16(ah2, blc, acc2, 0,0,0);
        bhc = bhn; blc = bln;
    }
    __syncthreads();   // all F1 reads done

    // ---- epilogue2: s_n = relu(feat2 + b2) . Wout, 32-col shfl reduce ----
    float* s2p  = R2;          // 128 floats
    float* srow = R2 + 128;    // 64 floats
    {
        const int   col2 = nt2*32 + l31;
        const float b2c  = b2[col2];
        const float woc  = Wout[col2];
        #pragma unroll
        for (int r = 0; r < 16; ++r) {
            float v = fmaxf(acc2[r] + b2c, 0.f) * woc;
            v += __shfl_xor(v, 1);
            v += __shfl_xor(v, 2);
            v += __shfl_xor(v, 4);
            v += __shfl_xor(v, 8);
            v += __shfl_xor(v, 16);
            if (l31 == 0) {
                int grow = m2*32 + (r & 3) + 8*(r >> 2) + 4*hs;
                s2p[nt2*64 + grow] = v;   // [colhalf][row]
            }
        }
    }
    __syncthreads();
    if (t < 64) srow[t] = s2p[t] + s2p[64 + t];
    __syncthreads();

    // ---- segmented sum over sorted batch, one atomic per run ----
    if (t < 64) {
        int node = n0 + t;
        int b = (node < N) ? batch[node] : -1;
        int pb = (t == 0) ? -2 : ((node - 1 < N) ? batch[node - 1] : -1);
        if (b >= 0 && b != pb) {
            float acc = 0.f;
            int j = t;
            while (j < 64 && (n0 + j) < N && batch[n0 + j] == b) { acc += srow[j]; ++j; }
            atomicAdd(&gf1d[b], acc);
        }
    }
}

__global__ void final_sigmoid(const float* __restrict__ gf1d, const float* __restrict__ bout,
                              float* __restrict__ out, int G)
{
    int g = blockIdx.x * 256 + threadIdx.x;
    if (g < G) out[g] = 1.f / (1.f + expf(-(gf1d[g] + bout[0])));
}

extern "C" void kernel_launch(void* const* d_in, const int* in_sizes, int n_in,
                              void* d_out, int out_size, void* d_ws, size_t ws_size,
                              hipStream_t stream)
{
    const float* h    = (const float*)d_in[0];
    const float* x    = (const float*)d_in[1];
    const int*   batch= (const int*)d_in[2];
    const float* W1   = (const float*)d_in[3];
    const float* b1   = (const float*)d_in[4];
    const float* W2   = (const float*)d_in[5];
    const float* b2   = (const float*)d_in[6];
    const float* Wout = (const float*)d_in[7];
    const float* bout = (const float*)d_in[8];
    float* out = (float*)d_out;

    const int N = in_sizes[2];
    const int G = out_size;

    // workspace layout (~305 KB total)
    char* ws = (char*)d_ws;
    float* gf1d = (float*)ws;                                  //   8,192 B
    float* zbuf = (float*)(ws + 8192);                         //   1,024 B (zeros)
    unsigned short* w1h = (unsigned short*)(ws + 9216);        // 229,376 B
    unsigned short* w2h = w1h + (size_t)W1P_SH8 * 8;           //  32,768 B
    unsigned short* w2l = w2h + (size_t)W2P_SH8 * 8;           //  32,768 B

    hipMemsetAsync(gf1d, 0, 9216, stream);   // gf accumulators + zero buffer
    pack_weights<<<(W1P_SH8 + W2P_SH8 + 255) / 256, 256, 0, stream>>>(W1, W2, w1h, w2h, w2l);
    fused_readout<<<(N + BM - 1) / BM, 256, 0, stream>>>(h, x, batch, w1h, w2h, w2l,
                                                         b1, b2, Wout, zbuf, gf1d, N);
    final_sigmoid<<<(G + 255) / 256, 256, 0, stream>>>(gf1d, bout, out, G);
}

// Round 14
// 169.302 us; speedup vs baseline: 3.0335x; 2.3216x over previous
//
#include <hip/hip_runtime.h>
#include <hip/hip_bf16.h>
#include <math.h>

// Fused GNN readout via bf16 MFMA (v_mfma_f32_32x32x16_bf16):
//   feat1 = relu(concat(h,x) @ W1 + b1)   [N,256]  GEMM1: K=400(pad 448), A=bf16 hi, B=W1 hi ONLY
//   feat2 = relu(feat1 @ W2 + b2)         [N,64]   GEMM2: K=256, A=bf16 hi, B=W2 hi+lo
//   s_n   = feat2 . Wout ; out = sigmoid(segment_sum(s_n) + bout)
// R14 = R8 VERBATIM (proven 207us / WRITE 9MB / 3 blocks/CU) + ONE delta:
//   W1 hi-only (absmax 1.907e-6 proven identical in R10/R12/R13).
//   NO sched_barrier (R13 evidence: it walls scheduling regions in the
//   unrolled chunk body -> live-range inflation -> 540MB scratch).
//   Counted vmcnt recomputed for the halved B-load counts with margin >=4:
//   exact newer-than-A(c) = 8 (c=0) / 16 (c=1) / 20 (c>=2);
//   waits: c==0 -> vmcnt(4), else vmcnt(12). Never 0, never exact.

typedef __attribute__((ext_vector_type(8)))  short short8v;
typedef __attribute__((ext_vector_type(16))) float f32x16;

#define G_NUM 2048
#define HID 200
#define EMB 200
#define DIN 400
#define NH1 256
#define NH2 64
#define BM  64
#define NKS1 28        // bf16 K-steps (of 16) for GEMM1, K padded 400->448
#define NCH  7         // 7 chunks of 64 fp32 cols
#define NKS2 16        // K-steps for GEMM2 (K=256)

#define W1P_SH8 (NKS1*8*64)   // 14336 fragments (16B each), hi plane only
#define W2P_SH8 (NKS2*2*64)   // 2048

__device__ __forceinline__ unsigned short f2bf(float f) {
    union { float f; unsigned u; } v; v.f = f;
    unsigned r = v.u + 0x7fffu + ((v.u >> 16) & 1u);   // RNE
    return (unsigned short)(r >> 16);
}
__device__ __forceinline__ float bf2f(unsigned short b) {
    union { unsigned u; float f; } v; v.u = ((unsigned)b) << 16;
    return v.f;
}
// 8 fp32 -> 8 bf16 (RNE) via packed converts
__device__ __forceinline__ short8v cvt8(float4 a, float4 b) {
    union { __hip_bfloat162 q[4]; short8v s8; } u;
    u.q[0] = __float22bfloat162_rn(make_float2(a.x, a.y));
    u.q[1] = __float22bfloat162_rn(make_float2(a.z, a.w));
    u.q[2] = __float22bfloat162_rn(make_float2(b.x, b.y));
    u.q[3] = __float22bfloat162_rn(make_float2(b.z, b.w));
    return u.s8;
}

// Pre-pack W1 (hi only) / W2 (hi+lo) into MFMA-fragment order.
// Fragment (ks, ntile, lane) holds 8 bf16: B[k0+j][col], k0=ks*16+(lane>>5)*8,
// col=ntile*32+(lane&31). Contiguous-8 k in BOTH A and B => any consistent
// hw k-permutation cancels in the dot product.
__global__ void pack_weights(const float* __restrict__ W1, const float* __restrict__ W2,
                             unsigned short* __restrict__ w1h,
                             unsigned short* __restrict__ w2h, unsigned short* __restrict__ w2l)
{
    int idx = blockIdx.x * 256 + threadIdx.x;
    if (idx < W1P_SH8) {
        int l  = idx & 63;
        int nt = (idx >> 6) & 7;
        int ks = idx >> 9;
        int col = nt * 32 + (l & 31);
        int k0  = ks * 16 + (l >> 5) * 8;
        short8v H;
        #pragma unroll
        for (int j = 0; j < 8; ++j) {
            int k = k0 + j;
            H[j] = (short)f2bf((k < DIN) ? W1[(size_t)k * NH1 + col] : 0.f);
        }
        ((short8v*)w1h)[idx] = H;
    } else if (idx < W1P_SH8 + W2P_SH8) {
        int i2 = idx - W1P_SH8;
        int l  = i2 & 63;
        int nt = (i2 >> 6) & 1;
        int ks = i2 >> 7;
        int col = nt * 32 + (l & 31);
        int k0  = ks * 16 + (l >> 5) * 8;
        short8v H, L;
        #pragma unroll
        for (int j = 0; j < 8; ++j) {
            float v = W2[(size_t)(k0 + j) * NH2 + col];
            unsigned short hh = f2bf(v);
            H[j] = (short)hh;
            L[j] = (short)f2bf(v - bf2f(hh));
        }
        ((short8v*)w2h)[i2] = H;
        ((short8v*)w2l)[i2] = L;
    }
}

__launch_bounds__(256, 3)
__global__ void fused_readout(const float* __restrict__ h, const float* __restrict__ x,
                              const int* __restrict__ batch,
                              const unsigned short* __restrict__ w1h,
                              const unsigned short* __restrict__ w2h, const unsigned short* __restrict__ w2l,
                              const float* __restrict__ b1, const float* __restrict__ b2,
                              const float* __restrict__ Wout, const float* __restrict__ zbuf,
                              float* __restrict__ gf1d, int N)
{
    // 49152 B LDS, time-multiplexed (R8 layout):
    //   [GEMM1] A fp32 ring: 3 bufs x [64 rows][64 fp32] = 49152 B
    //           (row stride 256 B; 16B-granule XOR swizzle c16 ^= row&15 applied
    //            on the GLOBAL SOURCE; LDS dest linear for global_load_lds)
    //   [GEMM2] F1h [64][256] bf16 = 32768 B (overlaps ring bufs 0-1)
    //   [pool ] s2p[2][64] f32 at 0, srow[64] f32 at byte 512
    __shared__ __align__(16) char lds[49152];
    unsigned short* F1h = (unsigned short*)lds;
    float* s2p  = (float*)lds;          // 128 floats
    float* srow = (float*)(lds + 512);  // 64 floats

    const int t    = threadIdx.x;
    const int lane = t & 63;
    const int w    = t >> 6;
    const int n0   = blockIdx.x * BM;
    const int l31  = lane & 31;
    const int hs   = lane >> 5;         // k-half select

    const short8v* W1H = (const short8v*)w1h;

    f32x16 acc00, acc01, acc10, acc11;
    #pragma unroll
    for (int r = 0; r < 16; ++r) { acc00[r] = 0.f; acc01[r] = 0.f; acc10[r] = 0.f; acc11[r] = 0.f; }

    // ---- helpers ----
    // issue 4 global_load_lds covering this wave's 16 rows of chunk CH into ring buffer BUF
    // dest: linear  BUF*16384 + brow*256 + lane*16
    // src : per-lane, pre-swizzled col16 = (lane&15) ^ (row&15); OOB -> zbuf
    #define AISSUE(CH, BUF) do {                                               \
        _Pragma("unroll")                                                      \
        for (int ii = 0; ii < 4; ++ii) {                                       \
            int brow = w*16 + ii*4;                                            \
            int row  = brow + (lane >> 4);                                     \
            int node = n0 + row;                                               \
            int colf = (CH)*64 + (((lane & 15) ^ (row & 15)) << 2);            \
            const float* src;                                                  \
            if (node >= N || colf >= DIN) src = zbuf + (lane & 15)*4;          \
            else if (colf < HID)          src = h + (size_t)node*HID + colf;   \
            else                          src = x + (size_t)node*EMB + (colf - HID); \
            __builtin_amdgcn_global_load_lds(                                  \
                (const __attribute__((address_space(1))) unsigned*)src,        \
                (__attribute__((address_space(3))) unsigned*)(lds + (BUF)*16384 + brow*256 + lane*16), \
                16, 0, 0);                                                     \
        } } while (0)

    // A fragment: row ROW, logical col16 pair {S*4+hs*2, +1} of ring buffer (byte base HB)
    #define AFRAG(HB, S, ROW)                                                  \
        cvt8(*(const float4*)(lds + (HB) + (ROW)*256 + ((((S)*4 + hs*2)     ^ ((ROW) & 15)) << 4)), \
             *(const float4*)(lds + (HB) + (ROW)*256 + ((((S)*4 + hs*2 + 1) ^ ((ROW) & 15)) << 4)))

    // load one k-step's 2 B hi-fragments into named regs
    #define BLOAD2(KS, H0, H1) do {                                            \
        size_t nb_ = ((size_t)((KS)*8 + w*2))*64 + lane;                       \
        H0 = W1H[nb_]; H1 = W1H[nb_ + 64]; } while (0)

    // ---- prologue: A chunks 0,1 in flight; B ksteps 0,1 in regs-in-flight ----
    AISSUE(0, 0);
    AISSUE(1, 1);
    short8v c0h0, c0h1;    // B(ks)   — consumed this k-step
    short8v c1h0, c1h1;    // B(ks+1)
    BLOAD2(0, c0h0, c0h1);
    BLOAD2(1, c1h0, c1h1);

    // ================= GEMM1: 7 chunks x 4 k-steps, counted-vmcnt pipeline =================
    #pragma unroll
    for (int c = 0; c < NCH; ++c) {
        // Loads newer than A(c) at this point (issue order: A0,A1,Bpro(4),
        // then per chunk: A(c+2):4 + B:8):
        //   c=0: 8   c=1: 16   c>=2: 20 (16 at c=6).
        // Counted waits with margin >=4 — never 0, never exact.
        if (c == 0) { asm volatile("s_waitcnt vmcnt(4)"  ::: "memory"); }
        else        { asm volatile("s_waitcnt vmcnt(12)" ::: "memory"); }
        __builtin_amdgcn_s_barrier();   // all waves' A(c) complete; ring (c+2)%3 free
        if (c + 2 < NCH) AISSUE(c + 2, (c + 2) % 3);

        const int hb = (c % 3) * 16384;
        #pragma unroll
        for (int s = 0; s < 4; ++s) {
            const int ks = c * 4 + s;
            // prefetch B(ks+2) (depth 2; dummy ks=0 at tail)
            short8v n2h0, n2h1;
            BLOAD2((ks + 2 < NKS1) ? ks + 2 : 0, n2h0, n2h1);
            // A fragments (LDS ring) + convert
            short8v ah0 = AFRAG(hb, s, l31);
            short8v ah1 = AFRAG(hb, s, 32 + l31);
            __builtin_amdgcn_s_setprio(1);
            acc00 = __builtin_amdgcn_mfma_f32_32x32x16_bf16(ah0, c0h0, acc00, 0,0,0);
            acc01 = __builtin_amdgcn_mfma_f32_32x32x16_bf16(ah0, c0h1, acc01, 0,0,0);
            acc10 = __builtin_amdgcn_mfma_f32_32x32x16_bf16(ah1, c0h0, acc10, 0,0,0);
            acc11 = __builtin_amdgcn_mfma_f32_32x32x16_bf16(ah1, c0h1, acc11, 0,0,0);
            __builtin_amdgcn_s_setprio(0);
            // rotate B pipeline
            c0h0 = c1h0; c0h1 = c1h1;
            c1h0 = n2h0; c1h1 = n2h1;
        }
    }
    #undef BLOAD2
    #undef AFRAG
    #undef AISSUE

    __syncthreads();   // all ring reads done; F1h may overwrite bufs 0-1

    // ---- epilogue1: bias + relu + bf16 (hi only) -> F1h (XOR-swizzled) ----
    // C/D layout: col = lane&31, row = (r&3) + 8*(r>>2) + 4*(lane>>5)
    const float b1c0 = b1[w*64 + l31];
    const float b1c1 = b1[w*64 + 32 + l31];
#define EPI1(ACC, MI, NI) do {                                            \
        int gcol = w*64 + (NI)*32 + l31;                                  \
        float bb = (NI) ? b1c1 : b1c0;                                    \
        _Pragma("unroll")                                                 \
        for (int r = 0; r < 16; ++r) {                                    \
            int grow = (MI)*32 + (r & 3) + 8*(r >> 2) + 4*hs;             \
            float v = fmaxf(ACC[r] + bb, 0.f);                            \
            int phys = grow*256 + (((gcol >> 3) ^ (grow & 31)) << 3) + (gcol & 7); \
            F1h[phys] = f2bf(v);                                          \
        } } while (0)
    EPI1(acc00, 0, 0); EPI1(acc01, 0, 1); EPI1(acc10, 1, 0); EPI1(acc11, 1, 1);
#undef EPI1
    __syncthreads();

    // ================= GEMM2: feat2 = relu(feat1 @ W2 + b2) =================
    // A = bf16(feat1) hi-only; B = W2 hi+lo (2 MFMAs per K-step).
    f32x16 acc2;
    #pragma unroll
    for (int r = 0; r < 16; ++r) acc2[r] = 0.f;
    const int m2   = w >> 1;      // node-row half
    const int nt2  = w & 1;       // col half
    const int arow = m2*32 + l31;

    const short8v* W2H = (const short8v*)w2h;
    const short8v* W2L = (const short8v*)w2l;
    short8v bhc = W2H[(size_t)nt2*64 + lane];
    short8v blc = W2L[(size_t)nt2*64 + lane];
    #pragma unroll
    for (int ks = 0; ks < NKS2; ++ks) {
        short8v bhn = bhc, bln = blc;
        if (ks + 1 < NKS2) {
            size_t nbase = (size_t)((ks + 1)*2 + nt2)*64 + lane;
            bhn = W2H[nbase];
            bln = W2L[nbase];
        }
        int blk  = (ks*2 + hs) ^ (arow & 31);
        short8v ah2 = *(const short8v*)&F1h[arow*256 + blk*8];
        acc2 = __builtin_amdgcn_mfma_f32_32x32x16_bf16(ah2, bhc, acc2, 0,0,0);
        acc2 = __builtin_amdgcn_mfma_f32_32x32x16_bf16(ah2, blc, acc2, 0,0,0);
        bhc = bhn; blc = bln;
    }
    __syncthreads();   // all F1 reads done; s2p/srow may now overwrite LDS

    // ---- epilogue2: s_n = relu(feat2 + b2) . Wout, 32-col shfl reduce ----
    {
        const int   col2 = nt2*32 + l31;
        const float b2c  = b2[col2];
        const float woc  = Wout[col2];
        #pragma unroll
        for (int r = 0; r < 16; ++r) {
            float v = fmaxf(acc2[r] + b2c, 0.f) * woc;
            v += __shfl_xor(v, 1);
            v += __shfl_xor(v, 2);
            v += __shfl_xor(v, 4);
            v += __shfl_xor(v, 8);
            v += __shfl_xor(v, 16);
            if (l31 == 0) {
                int grow = m2*32 + (r & 3) + 8*(r >> 2) + 4*hs;
                s2p[nt2*64 + grow] = v;   // [colhalf][row]
            }
        }
    }
    __syncthreads();
    if (t < 64) srow[t] = s2p[t] + s2p[64 + t];
    __syncthreads();

    // ---- segmented sum over sorted batch, one atomic per run ----
    if (t < 64) {
        int node = n0 + t;
        int b = (node < N) ? batch[node] : -1;
        int pb = (t == 0) ? -2 : ((node - 1 < N) ? batch[node - 1] : -1);
        if (b >= 0 && b != pb) {
            float acc = 0.f;
            int j = t;
            while (j < 64 && (n0 + j) < N && batch[n0 + j] == b) { acc += srow[j]; ++j; }
            atomicAdd(&gf1d[b], acc);
        }
    }
}

__global__ void final_sigmoid(const float* __restrict__ gf1d, const float* __restrict__ bout,
                              float* __restrict__ out, int G)
{
    int g = blockIdx.x * 256 + threadIdx.x;
    if (g < G) out[g] = 1.f / (1.f + expf(-(gf1d[g] + bout[0])));
}

extern "C" void kernel_launch(void* const* d_in, const int* in_sizes, int n_in,
                              void* d_out, int out_size, void* d_ws, size_t ws_size,
                              hipStream_t stream)
{
    const float* h    = (const float*)d_in[0];
    const float* x    = (const float*)d_in[1];
    const int*   batch= (const int*)d_in[2];
    const float* W1   = (const float*)d_in[3];
    const float* b1   = (const float*)d_in[4];
    const float* W2   = (const float*)d_in[5];
    const float* b2   = (const float*)d_in[6];
    const float* Wout = (const float*)d_in[7];
    const float* bout = (const float*)d_in[8];
    float* out = (float*)d_out;

    const int N = in_sizes[2];
    const int G = out_size;

    // workspace layout (~305 KB total)
    char* ws = (char*)d_ws;
    float* gf1d = (float*)ws;                                  //   8,192 B
    float* zbuf = (float*)(ws + 8192);                         //   1,024 B (zeros)
    unsigned short* w1h = (unsigned short*)(ws + 9216);        // 229,376 B
    unsigned short* w2h = w1h + (size_t)W1P_SH8 * 8;           //  32,768 B
    unsigned short* w2l = w2h + (size_t)W2P_SH8 * 8;           //  32,768 B

    hipMemsetAsync(gf1d, 0, 9216, stream);   // gf accumulators + zero buffer
    pack_weights<<<(W1P_SH8 + W2P_SH8 + 255) / 256, 256, 0, stream>>>(W1, W2, w1h, w2h, w2l);
    fused_readout<<<(N + BM - 1) / BM, 256, 0, stream>>>(h, x, batch, w1h, w2h, w2l,
                                                         b1, b2, Wout, zbuf, gf1d, N);
    final_sigmoid<<<(G + 255) / 256, 256, 0, stream>>>(gf1d, bout, out, G);
}

// Round 15
// 165.269 us; speedup vs baseline: 3.1075x; 1.0244x over previous
//
#include <hip/hip_runtime.h>
#include <hip/hip_bf16.h>
#include <math.h>

// Fused GNN readout via bf16 MFMA (v_mfma_f32_32x32x16_bf16):
//   feat1 = relu(concat(h,x) @ W1 + b1)   [N,256]  GEMM1: K=400(pad 448), A=bf16 hi, B=W1 hi ONLY
//   feat2 = relu(feat1 @ W2 + b2)         [N,64]   GEMM2: K=256, A=bf16 hi, B=W2 hi+lo
//   s_n   = feat2 . Wout ; out = sigmoid(segment_sum(s_n) + bout)
// R15 = R14 (169us, WRITE 105KB, absmax 1.9e-6) + register-cap fix:
//   R14 sat at 76 arch + 64 acc = 140 unified regs -> only 2 waves/SIMD
//   (occupancy steps at 64/128/256) -> Occupancy 23%. The LDS cap (3 blocks)
//   was NOT the binder; the reg cap was.
//   - __launch_bounds__(256,4): allocator targets <=128 unified (arch <=64)
//     -> 3 resident blocks = 12 waves/CU = 37.5% (1.5x concurrency).
//   - setprio dropped (m190: no win for lockstep GEMM).
//   Decisive check: WRITE_SIZE must stay ~105KB. If it explodes, /4 spilled
//   and the revert is R14 + A-frag prefetch.

typedef __attribute__((ext_vector_type(8)))  short short8v;
typedef __attribute__((ext_vector_type(16))) float f32x16;

#define G_NUM 2048
#define HID 200
#define EMB 200
#define DIN 400
#define NH1 256
#define NH2 64
#define BM  64
#define NKS1 28        // bf16 K-steps (of 16) for GEMM1, K padded 400->448
#define NCH  7         // 7 chunks of 64 fp32 cols
#define NKS2 16        // K-steps for GEMM2 (K=256)

#define W1P_SH8 (NKS1*8*64)   // 14336 fragments (16B each), hi plane only
#define W2P_SH8 (NKS2*2*64)   // 2048

__device__ __forceinline__ unsigned short f2bf(float f) {
    union { float f; unsigned u; } v; v.f = f;
    unsigned r = v.u + 0x7fffu + ((v.u >> 16) & 1u);   // RNE
    return (unsigned short)(r >> 16);
}
__device__ __forceinline__ float bf2f(unsigned short b) {
    union { unsigned u; float f; } v; v.u = ((unsigned)b) << 16;
    return v.f;
}
// 8 fp32 -> 8 bf16 (RNE) via packed converts
__device__ __forceinline__ short8v cvt8(float4 a, float4 b) {
    union { __hip_bfloat162 q[4]; short8v s8; } u;
    u.q[0] = __float22bfloat162_rn(make_float2(a.x, a.y));
    u.q[1] = __float22bfloat162_rn(make_float2(a.z, a.w));
    u.q[2] = __float22bfloat162_rn(make_float2(b.x, b.y));
    u.q[3] = __float22bfloat162_rn(make_float2(b.z, b.w));
    return u.s8;
}

// Pre-pack W1 (hi only) / W2 (hi+lo) into MFMA-fragment order.
// Fragment (ks, ntile, lane) holds 8 bf16: B[k0+j][col], k0=ks*16+(lane>>5)*8,
// col=ntile*32+(lane&31). Contiguous-8 k in BOTH A and B => any consistent
// hw k-permutation cancels in the dot product.
__global__ void pack_weights(const float* __restrict__ W1, const float* __restrict__ W2,
                             unsigned short* __restrict__ w1h,
                             unsigned short* __restrict__ w2h, unsigned short* __restrict__ w2l)
{
    int idx = blockIdx.x * 256 + threadIdx.x;
    if (idx < W1P_SH8) {
        int l  = idx & 63;
        int nt = (idx >> 6) & 7;
        int ks = idx >> 9;
        int col = nt * 32 + (l & 31);
        int k0  = ks * 16 + (l >> 5) * 8;
        short8v H;
        #pragma unroll
        for (int j = 0; j < 8; ++j) {
            int k = k0 + j;
            H[j] = (short)f2bf((k < DIN) ? W1[(size_t)k * NH1 + col] : 0.f);
        }
        ((short8v*)w1h)[idx] = H;
    } else if (idx < W1P_SH8 + W2P_SH8) {
        int i2 = idx - W1P_SH8;
        int l  = i2 & 63;
        int nt = (i2 >> 6) & 1;
        int ks = i2 >> 7;
        int col = nt * 32 + (l & 31);
        int k0  = ks * 16 + (l >> 5) * 8;
        short8v H, L;
        #pragma unroll
        for (int j = 0; j < 8; ++j) {
            float v = W2[(size_t)(k0 + j) * NH2 + col];
            unsigned short hh = f2bf(v);
            H[j] = (short)hh;
            L[j] = (short)f2bf(v - bf2f(hh));
        }
        ((short8v*)w2h)[i2] = H;
        ((short8v*)w2l)[i2] = L;
    }
}

__launch_bounds__(256, 4)
__global__ void fused_readout(const float* __restrict__ h, const float* __restrict__ x,
                              const int* __restrict__ batch,
                              const unsigned short* __restrict__ w1h,
                              const unsigned short* __restrict__ w2h, const unsigned short* __restrict__ w2l,
                              const float* __restrict__ b1, const float* __restrict__ b2,
                              const float* __restrict__ Wout, const float* __restrict__ zbuf,
                              float* __restrict__ gf1d, int N)
{
    // 49152 B LDS, time-multiplexed (R8/R14 layout):
    //   [GEMM1] A fp32 ring: 3 bufs x [64 rows][64 fp32] = 49152 B
    //           (row stride 256 B; 16B-granule XOR swizzle c16 ^= row&15 applied
    //            on the GLOBAL SOURCE; LDS dest linear for global_load_lds)
    //   [GEMM2] F1h [64][256] bf16 = 32768 B (overlaps ring bufs 0-1)
    //   [pool ] s2p[2][64] f32 at 0, srow[64] f32 at byte 512
    __shared__ __align__(16) char lds[49152];
    unsigned short* F1h = (unsigned short*)lds;
    float* s2p  = (float*)lds;          // 128 floats
    float* srow = (float*)(lds + 512);  // 64 floats

    const int t    = threadIdx.x;
    const int lane = t & 63;
    const int w    = t >> 6;
    const int n0   = blockIdx.x * BM;
    const int l31  = lane & 31;
    const int hs   = lane >> 5;         // k-half select

    const short8v* W1H = (const short8v*)w1h;

    f32x16 acc00, acc01, acc10, acc11;
    #pragma unroll
    for (int r = 0; r < 16; ++r) { acc00[r] = 0.f; acc01[r] = 0.f; acc10[r] = 0.f; acc11[r] = 0.f; }

    // ---- helpers ----
    // issue 4 global_load_lds covering this wave's 16 rows of chunk CH into ring buffer BUF
    // dest: linear  BUF*16384 + brow*256 + lane*16
    // src : per-lane, pre-swizzled col16 = (lane&15) ^ (row&15); OOB -> zbuf
    #define AISSUE(CH, BUF) do {                                               \
        _Pragma("unroll")                                                      \
        for (int ii = 0; ii < 4; ++ii) {                                       \
            int brow = w*16 + ii*4;                                            \
            int row  = brow + (lane >> 4);                                     \
            int node = n0 + row;                                               \
            int colf = (CH)*64 + (((lane & 15) ^ (row & 15)) << 2);            \
            const float* src;                                                  \
            if (node >= N || colf >= DIN) src = zbuf + (lane & 15)*4;          \
            else if (colf < HID)          src = h + (size_t)node*HID + colf;   \
            else                          src = x + (size_t)node*EMB + (colf - HID); \
            __builtin_amdgcn_global_load_lds(                                  \
                (const __attribute__((address_space(1))) unsigned*)src,        \
                (__attribute__((address_space(3))) unsigned*)(lds + (BUF)*16384 + brow*256 + lane*16), \
                16, 0, 0);                                                     \
        } } while (0)

    // A fragment: row ROW, logical col16 pair {S*4+hs*2, +1} of ring buffer (byte base HB)
    #define AFRAG(HB, S, ROW)                                                  \
        cvt8(*(const float4*)(lds + (HB) + (ROW)*256 + ((((S)*4 + hs*2)     ^ ((ROW) & 15)) << 4)), \
             *(const float4*)(lds + (HB) + (ROW)*256 + ((((S)*4 + hs*2 + 1) ^ ((ROW) & 15)) << 4)))

    // load one k-step's 2 B hi-fragments into named regs
    #define BLOAD2(KS, H0, H1) do {                                            \
        size_t nb_ = ((size_t)((KS)*8 + w*2))*64 + lane;                       \
        H0 = W1H[nb_]; H1 = W1H[nb_ + 64]; } while (0)

    // ---- prologue: A chunks 0,1 in flight; B ksteps 0,1 in regs-in-flight ----
    AISSUE(0, 0);
    AISSUE(1, 1);
    short8v c0h0, c0h1;    // B(ks)   — consumed this k-step
    short8v c1h0, c1h1;    // B(ks+1)
    BLOAD2(0, c0h0, c0h1);
    BLOAD2(1, c1h0, c1h1);

    // ================= GEMM1: 7 chunks x 4 k-steps, counted-vmcnt pipeline =================
    #pragma unroll
    for (int c = 0; c < NCH; ++c) {
        // Loads newer than A(c) at this point (issue order: A0,A1,Bpro(4),
        // then per chunk: A(c+2):4 + B:8):
        //   c=0: 8   c=1: 16   c>=2: 20 (16 at c=6).
        // Counted waits with margin >=4 — never 0, never exact.
        if (c == 0) { asm volatile("s_waitcnt vmcnt(4)"  ::: "memory"); }
        else        { asm volatile("s_waitcnt vmcnt(12)" ::: "memory"); }
        __builtin_amdgcn_s_barrier();   // all waves' A(c) complete; ring (c+2)%3 free
        if (c + 2 < NCH) AISSUE(c + 2, (c + 2) % 3);

        const int hb = (c % 3) * 16384;
        #pragma unroll
        for (int s = 0; s < 4; ++s) {
            const int ks = c * 4 + s;
            // prefetch B(ks+2) (depth 2; dummy ks=0 at tail)
            short8v n2h0, n2h1;
            BLOAD2((ks + 2 < NKS1) ? ks + 2 : 0, n2h0, n2h1);
            // A fragments (LDS ring) + convert
            short8v ah0 = AFRAG(hb, s, l31);
            short8v ah1 = AFRAG(hb, s, 32 + l31);
            acc00 = __builtin_amdgcn_mfma_f32_32x32x16_bf16(ah0, c0h0, acc00, 0,0,0);
            acc01 = __builtin_amdgcn_mfma_f32_32x32x16_bf16(ah0, c0h1, acc01, 0,0,0);
            acc10 = __builtin_amdgcn_mfma_f32_32x32x16_bf16(ah1, c0h0, acc10, 0,0,0);
            acc11 = __builtin_amdgcn_mfma_f32_32x32x16_bf16(ah1, c0h1, acc11, 0,0,0);
            // rotate B pipeline
            c0h0 = c1h0; c0h1 = c1h1;
            c1h0 = n2h0; c1h1 = n2h1;
        }
    }
    #undef BLOAD2
    #undef AFRAG
    #undef AISSUE

    __syncthreads();   // all ring reads done; F1h may overwrite bufs 0-1

    // ---- epilogue1: bias + relu + bf16 (hi only) -> F1h (XOR-swizzled) ----
    // C/D layout: col = lane&31, row = (r&3) + 8*(r>>2) + 4*(lane>>5)
    const float b1c0 = b1[w*64 + l31];
    const float b1c1 = b1[w*64 + 32 + l31];
#define EPI1(ACC, MI, NI) do {                                            \
        int gcol = w*64 + (NI)*32 + l31;                                  \
        float bb = (NI) ? b1c1 : b1c0;                                    \
        _Pragma("unroll")                                                 \
        for (int r = 0; r < 16; ++r) {                                    \
            int grow = (MI)*32 + (r & 3) + 8*(r >> 2) + 4*hs;             \
            float v = fmaxf(ACC[r] + bb, 0.f);                            \
            int phys = grow*256 + (((gcol >> 3) ^ (grow & 31)) << 3) + (gcol & 7); \
            F1h[phys] = f2bf(v);                                          \
        } } while (0)
    EPI1(acc00, 0, 0); EPI1(acc01, 0, 1); EPI1(acc10, 1, 0); EPI1(acc11, 1, 1);
#undef EPI1
    __syncthreads();

    // ================= GEMM2: feat2 = relu(feat1 @ W2 + b2) =================
    // A = bf16(feat1) hi-only; B = W2 hi+lo (2 MFMAs per K-step).
    f32x16 acc2;
    #pragma unroll
    for (int r = 0; r < 16; ++r) acc2[r] = 0.f;
    const int m2   = w >> 1;      // node-row half
    const int nt2  = w & 1;       // col half
    const int arow = m2*32 + l31;

    const short8v* W2H = (const short8v*)w2h;
    const short8v* W2L = (const short8v*)w2l;
    short8v bhc = W2H[(size_t)nt2*64 + lane];
    short8v blc = W2L[(size_t)nt2*64 + lane];
    #pragma unroll
    for (int ks = 0; ks < NKS2; ++ks) {
        short8v bhn = bhc, bln = blc;
        if (ks + 1 < NKS2) {
            size_t nbase = (size_t)((ks + 1)*2 + nt2)*64 + lane;
            bhn = W2H[nbase];
            bln = W2L[nbase];
        }
        int blk  = (ks*2 + hs) ^ (arow & 31);
        short8v ah2 = *(const short8v*)&F1h[arow*256 + blk*8];
        acc2 = __builtin_amdgcn_mfma_f32_32x32x16_bf16(ah2, bhc, acc2, 0,0,0);
        acc2 = __builtin_amdgcn_mfma_f32_32x32x16_bf16(ah2, blc, acc2, 0,0,0);
        bhc = bhn; blc = bln;
    }
    __syncthreads();   // all F1 reads done; s2p/srow may now overwrite LDS

    // ---- epilogue2: s_n = relu(feat2 + b2) . Wout, 32-col shfl reduce ----
    {
        const int   col2 = nt2*32 + l31;
        const float b2c  = b2[col2];
        const float woc  = Wout[col2];
        #pragma unroll
        for (int r = 0; r < 16; ++r) {
            float v = fmaxf(acc2[r] + b2c, 0.f) * woc;
            v += __shfl_xor(v, 1);
            v += __shfl_xor(v, 2);
            v += __shfl_xor(v, 4);
            v += __shfl_xor(v, 8);
            v += __shfl_xor(v, 16);
            if (l31 == 0) {
                int grow = m2*32 + (r & 3) + 8*(r >> 2) + 4*hs;
                s2p[nt2*64 + grow] = v;   // [colhalf][row]
            }
        }
    }
    __syncthreads();
    if (t < 64) srow[t] = s2p[t] + s2p[64 + t];
    __syncthreads();

    // ---- segmented sum over sorted batch, one atomic per run ----
    if (t < 64) {
        int node = n0 + t;
        int b = (node < N) ? batch[node] : -1;
        int pb = (t == 0) ? -2 : ((node - 1 < N) ? batch[node - 1] : -1);
        if (b >= 0 && b != pb) {
            float acc = 0.f;
            int j = t;
            while (j < 64 && (n0 + j) < N && batch[n0 + j] == b) { acc += srow[j]; ++j; }
            atomicAdd(&gf1d[b], acc);
        }
    }
}

__global__ void final_sigmoid(const float* __restrict__ gf1d, const float* __restrict__ bout,
                              float* __restrict__ out, int G)
{
    int g = blockIdx.x * 256 + threadIdx.x;
    if (g < G) out[g] = 1.f / (1.f + expf(-(gf1d[g] + bout[0])));
}

extern "C" void kernel_launch(void* const* d_in, const int* in_sizes, int n_in,
                              void* d_out, int out_size, void* d_ws, size_t ws_size,
                              hipStream_t stream)
{
    const float* h    = (const float*)d_in[0];
    const float* x    = (const float*)d_in[1];
    const int*   batch= (const int*)d_in[2];
    const float* W1   = (const float*)d_in[3];
    const float* b1   = (const float*)d_in[4];
    const float* W2   = (const float*)d_in[5];
    const float* b2   = (const float*)d_in[6];
    const float* Wout = (const float*)d_in[7];
    const float* bout = (const float*)d_in[8];
    float* out = (float*)d_out;

    const int N = in_sizes[2];
    const int G = out_size;

    // workspace layout (~305 KB total)
    char* ws = (char*)d_ws;
    float* gf1d = (float*)ws;                                  //   8,192 B
    float* zbuf = (float*)(ws + 8192);                         //   1,024 B (zeros)
    unsigned short* w1h = (unsigned short*)(ws + 9216);        // 229,376 B
    unsigned short* w2h = w1h + (size_t)W1P_SH8 * 8;           //  32,768 B
    unsigned short* w2l = w2h + (size_t)W2P_SH8 * 8;           //  32,768 B

    hipMemsetAsync(gf1d, 0, 9216, stream);   // gf accumulators + zero buffer
    pack_weights<<<(W1P_SH8 + W2P_SH8 + 255) / 256, 256, 0, stream>>>(W1, W2, w1h, w2h, w2l);
    fused_readout<<<(N + BM - 1) / BM, 256, 0, stream>>>(h, x, batch, w1h, w2h, w2l,
                                                         b1, b2, Wout, zbuf, gf1d, N);
    final_sigmoid<<<(G + 255) / 256, 256, 0, stream>>>(gf1d, bout, out, G);
}